// Round 14
// baseline (452.257 us; speedup 1.0000x reference)
//
#include <hip/hip_runtime.h>
#include <cstdint>
#include <cstddef>

#define D_MODEL 1024
#define DIN     2048
#define NSTATE  16
#define LSEQ    2048
#define NBATCH  2
#define NROWS   (NBATCH*LSEQ)   // 4096
#define NCOL    (DIN + 128)     // 2176 = dt(2048) | B(16) | C(16) | pad(96)
#define CCH     64              // scan chunks
#define TC      (LSEQ/CCH)      // 32 steps per chunk

typedef float  f32x4  __attribute__((ext_vector_type(4)));
typedef short  bf16x8 __attribute__((ext_vector_type(8)));
typedef unsigned short us8 __attribute__((ext_vector_type(8)));

__device__ __forceinline__ unsigned short f2bf(float f) {
  union { float f; unsigned u; } c; c.f = f;
  unsigned x = c.u + 0x7fffu + ((c.u >> 16) & 1u);   // RNE
  return (unsigned short)(x >> 16);
}
__device__ __forceinline__ float bf2f(unsigned short u) {
  union { unsigned u; float f; } c; c.u = (unsigned)u << 16; return c.f;
}
// native transcendentals (v_exp_f32 / v_log_f32 / v_rcp_f32), NOT precise libm
__device__ __forceinline__ float sigmoidf_(float x) {
  return __builtin_amdgcn_rcpf(1.f + __expf(-x));
}
__device__ __forceinline__ float softplusf_(float x) {   // fast, stable
  return fmaxf(x, 0.f) + __logf(1.f + __expf(-fabsf(x)));
}

// async global->LDS, 16B per lane; lds dest = wave-uniform base + lane*16
__device__ __forceinline__ void gll16(const void* g, void* l) {
  __builtin_amdgcn_global_load_lds(
      (const __attribute__((address_space(1))) void*)g,
      (__attribute__((address_space(3))) void*)l, 16, 0, 0);
}

// ---------------- layernorm (one row per block, D=1024) ----------------
// Optionally fuses: pos-add (pos!=null), Wout-partial sum + b_out (P!=null),
// residual update write (Xw!=null).
__global__ __launch_bounds__(256) void ln_kernel(const float* __restrict__ Xin,
    const float* __restrict__ pos, const unsigned short* __restrict__ P, int nP,
    const float* __restrict__ bex, const float* __restrict__ w,
    const float* __restrict__ b, unsigned short* __restrict__ outB,
    float* __restrict__ outF, float* __restrict__ Xw) {
  const int row = blockIdx.x, t = threadIdx.x;
  float4 v = *(const float4*)(Xin + (size_t)row * D_MODEL + t * 4);
  if (pos) {
    const float4 p = *(const float4*)(pos + (size_t)(row & (LSEQ - 1)) * D_MODEL + t * 4);
    v.x += p.x; v.y += p.y; v.z += p.z; v.w += p.w;
  }
  if (P) {
    const size_t MN = (size_t)NROWS * D_MODEL;
    const size_t e = (size_t)row * D_MODEL + t * 4;
    float a0 = 0.f, a1 = 0.f, a2 = 0.f, a3 = 0.f;
#pragma unroll 2
    for (int k = 0; k < nP; k++) {
      const ushort4 u = *(const ushort4*)(P + k * MN + e);
      a0 += bf2f(u.x); a1 += bf2f(u.y); a2 += bf2f(u.z); a3 += bf2f(u.w);
    }
    const float4 be = *(const float4*)(bex + t * 4);
    v.x += a0 + be.x; v.y += a1 + be.y; v.z += a2 + be.z; v.w += a3 + be.w;
  }
  if (Xw) *(float4*)(Xw + (size_t)row * D_MODEL + t * 4) = v;
  float s  = v.x + v.y + v.z + v.w;
  float s2 = v.x * v.x + v.y * v.y + v.z * v.z + v.w * v.w;
#pragma unroll
  for (int o = 1; o < 64; o <<= 1) { s += __shfl_xor(s, o, 64); s2 += __shfl_xor(s2, o, 64); }
  __shared__ float ps[8];
  int wv = t >> 6;
  if ((t & 63) == 0) { ps[wv] = s; ps[wv + 4] = s2; }
  __syncthreads();
  s  = ps[0] + ps[1] + ps[2] + ps[3];
  s2 = ps[4] + ps[5] + ps[6] + ps[7];
  float mean = s * (1.f / D_MODEL);
  float var  = s2 * (1.f / D_MODEL) - mean * mean;
  float rs   = rsqrtf(var + 1e-5f);
  const float4 wv4 = *(const float4*)(w + t * 4);
  const float4 bv4 = *(const float4*)(b + t * 4);
  float o0 = (v.x - mean) * rs * wv4.x + bv4.x;
  float o1 = (v.y - mean) * rs * wv4.y + bv4.y;
  float o2 = (v.z - mean) * rs * wv4.z + bv4.z;
  float o3 = (v.w - mean) * rs * wv4.w + bv4.w;
  if (outB) {
    ushort4 o; o.x = f2bf(o0); o.y = f2bf(o1); o.z = f2bf(o2); o.w = f2bf(o3);
    *(ushort4*)(outB + (size_t)row * D_MODEL + t * 4) = o;
  } else {
    float4 o; o.x = o0; o.y = o1; o.z = o2; o.w = o3;
    *(float4*)(outF + (size_t)row * D_MODEL + t * 4) = o;
  }
}

// ---------------- transpose + fp32->bf16: out[n][k] = in[k][n] ----------------
// blockIdx.z = layer (in/out advanced by per-layer strides).
__global__ __launch_bounds__(256) void tcvt_kernel(const float* __restrict__ in0,
    unsigned short* __restrict__ out0, int K_, int N_,
    size_t inLS, size_t outLS) {
  const float* in = in0 + (size_t)blockIdx.z * inLS;
  unsigned short* out = out0 + (size_t)blockIdx.z * outLS;
  __shared__ float tile[64][68];
  int n0 = blockIdx.x * 64, k0 = blockIdx.y * 64;
  int t = threadIdx.x;
  int r = t >> 4, cc = (t & 15) * 4;
#pragma unroll
  for (int j = 0; j < 4; j++) {
    const float4 v = *(const float4*)(in + (size_t)(k0 + r + j * 16) * N_ + n0 + cc);
    tile[r + j * 16][cc + 0] = v.x; tile[r + j * 16][cc + 1] = v.y;
    tile[r + j * 16][cc + 2] = v.z; tile[r + j * 16][cc + 3] = v.w;
  }
  __syncthreads();
  int nr = t >> 2, kc = (t & 3) * 16;
  unsigned u[8];
#pragma unroll
  for (int i = 0; i < 8; i++) {
    unsigned lo = f2bf(tile[kc + 2 * i][nr]);
    unsigned hi = f2bf(tile[kc + 2 * i + 1][nr]);
    u[i] = lo | (hi << 16);
  }
  uint4* dst = (uint4*)(out + (size_t)(n0 + nr) * K_ + k0 + kc);
  uint4 w0; w0.x = u[0]; w0.y = u[1]; w0.z = u[2]; w0.w = u[3];
  uint4 w1; w1.x = u[4]; w1.y = u[5]; w1.z = u[6]; w1.w = u[7];
  dst[0] = w0; dst[1] = w1;
}

// ---- merged prep: WB/WC^T rows 2048..2079, zero pad rows 2080..2175, bias2 ----
// blockIdx.y = layer.
__global__ __launch_bounds__(256) void wprep_kernel(const float* __restrict__ WB0,
    const float* __restrict__ WC0, const float* __restrict__ b_dt0,
    unsigned short* __restrict__ Wt0, float* __restrict__ bias20) {
  const int L = blockIdx.y;
  const float* WB = WB0 + (size_t)L * DIN * NSTATE;
  const float* WC = WC0 + (size_t)L * DIN * NSTATE;
  const float* b_dt = b_dt0 + (size_t)L * DIN;
  unsigned short* Wt = Wt0 + (size_t)L * NCOL * DIN;
  float* bias2 = bias20 + (size_t)L * NCOL;
  int id = blockIdx.x * 256 + threadIdx.x;
  if (id < 65536) {                                     // 32 x 2048 transpose fill
    int k = id & (DIN - 1);
    int n2 = id >> 11;
    float v = (n2 < NSTATE) ? WB[(size_t)k * NSTATE + n2]
                            : WC[(size_t)k * NSTATE + (n2 - NSTATE)];
    Wt[(size_t)(DIN + n2) * DIN + k] = f2bf(v);
  } else if (id < 90112) {                              // zero 96x2048 bf16, x8 vec
    int z = id - 65536;
    uint4 zz; zz.x = zz.y = zz.z = zz.w = 0u;
    *(uint4*)(Wt + (size_t)2080 * DIN + (size_t)z * 8) = zz;
  } else if (id < 90112 + NCOL) {                       // bias2
    int i = id - 90112;
    bias2[i] = (i < DIN) ? b_dt[i] : 0.f;
  }
}

// ---------------- bf16 MFMA GEMM, depth-2 pipeline (3 LDS bufs) -----------
// out[ks] = bf16(A[M][kRange] @ Bt[N][kRange]^T + bias(ks==0)).
// Block tile (2*WM) x 128, 4 waves as 2Mx2N, wave-tile WM x 64. WM=64: the
// r11-proven config (68 VGPR, 48KB LDS, 3 blk/CU). WM=128: doubles FLOP per
// LDS-read-byte (32 -> 42.7) for LDS-BW-bound shapes (dt GEMM), 72KB LDS,
// ~210 VGPR, 2 blk/CU. Counted vmcnt keeps one STAGE in flight across two
// compute phases. K-col XOR swizzle on row bits 1-2 (conflict-free, r11).
// Epilogue bounces C through LDS for 16B coalesced stores. gridDim.z = split-K.
template <int WM>
__global__ __launch_bounds__(256, 2) void gemm_kernel(
    const unsigned short* __restrict__ A, const unsigned short* __restrict__ Bt,
    const float* __restrict__ bias, unsigned short* __restrict__ outP,
    int M, int N, int Kfull, int kLen) {
  constexpr int TM   = 2 * WM;        // block M size
  constexpr int MF   = WM / 16;       // A frags per wave
  constexpr int AC   = TM / 64;       // gll16 calls for A per stage
  constexpr int ABUF = TM * 32;       // ushorts per A buffer
  __shared__ unsigned short smem[3 * (ABUF + 4096)];
  unsigned short* sA = smem;
  unsigned short* sB = smem + 3 * ABUF;
  const int t = threadIdx.x;
  const int lane = t & 63, wave = t >> 6;
  const int wr = wave >> 1, wc = wave & 1;

  // XCD-chunked bijective swizzle over linearized 3D grid
  const int gx = gridDim.x, gy = gridDim.y;
  const int orig = (blockIdx.z * gy + blockIdx.y) * gx + blockIdx.x;
  const int nwg = gx * gy * gridDim.z;
  const int q = nwg >> 3, r = nwg & 7;
  const int xcd = orig & 7, pp = orig >> 3;
  const int wgid = (xcd < r) ? (xcd * (q + 1) + pp)
                             : (r * (q + 1) + (xcd - r) * q + pp);
  const int nt = wgid % gx;
  const int mt = (wgid / gx) % gy;
  const int ks = wgid / (gx * gy);
  const int m0 = mt * TM, n0 = nt * 128;

  const int ar = t >> 2;                               // staging row (0..63)
  const int acs = (((t & 3) ^ ((ar >> 1) & 3)) << 3);  // swizzled source K-col
  const int wseg = wave * 16 * 32;                     // wave-uniform LDS base
  const int lr = lane & 15;
  const int swA = (((lane >> 4) ^ ((lr >> 1) & 3)) << 3); // swizzled read K-col

  f32x4 acc[MF][4];
#pragma unroll
  for (int m = 0; m < MF; m++)
#pragma unroll
    for (int n = 0; n < 4; n++) acc[m][n] = (f32x4)0.f;

  const int kBeg = ks * kLen;
  const int NT = kLen >> 5;

  auto STAGE = [&](int bi, int k0) {
#pragma unroll
    for (int c = 0; c < AC; c++)
      gll16(A + (size_t)(m0 + c * 64 + ar) * Kfull + k0 + acs,
            &sA[bi * ABUF + c * 2048 + wseg]);
    gll16(Bt + (size_t)(n0 + ar) * Kfull + k0 + acs,      &sB[bi * 4096 + wseg]);
    gll16(Bt + (size_t)(n0 + 64 + ar) * Kfull + k0 + acs, &sB[bi * 4096 + 2048 + wseg]);
  };
  auto COMPUTE = [&](int bi) {
    bf16x8 af[MF], bg[4];
#pragma unroll
    for (int m = 0; m < MF; m++)
      af[m] = *(const bf16x8*)(&sA[bi * ABUF + (wr * WM + m * 16 + lr) * 32 + swA]);
#pragma unroll
    for (int n = 0; n < 4; n++)
      bg[n] = *(const bf16x8*)(&sB[bi * 4096 + (wc * 64 + n * 16 + lr) * 32 + swA]);
#pragma unroll
    for (int m = 0; m < MF; m++)
#pragma unroll
      for (int n = 0; n < 4; n++)
        acc[m][n] = __builtin_amdgcn_mfma_f32_16x16x32_bf16(af[m], bg[n], acc[m][n], 0, 0, 0);
  };

  STAGE(0, kBeg); STAGE(1, kBeg + 32);                 // depth-2 prologue
  for (int tt = 0; tt < NT - 1; ++tt) {
    // wait until the oldest STAGE's (AC+2) loads have landed
    if constexpr (WM == 64) asm volatile("s_waitcnt vmcnt(4)" ::: "memory");
    else                    asm volatile("s_waitcnt vmcnt(6)" ::: "memory");
    __builtin_amdgcn_s_barrier();                      // all waves' tile ready
    if (tt + 2 < NT) STAGE((tt + 2) % 3, kBeg + ((tt + 2) << 5));
    COMPUTE(tt % 3);
  }
  asm volatile("s_waitcnt vmcnt(0)" ::: "memory");     // tail drain
  __builtin_amdgcn_s_barrier();
  COMPUTE((NT - 1) % 3);

  // ---- epilogue: bounce C quadrant through LDS -> 16B coalesced stores ----
  __syncthreads();                                     // staging LDS now free
  unsigned short* sC = smem + wave * (WM * 64);        // WM x 64 bf16, 128B rows
  const int lq = lane >> 4;
#pragma unroll
  for (int m = 0; m < MF; m++)
#pragma unroll
    for (int n = 0; n < 4; n++) {
      const int lcol = n * 16 + lr;
      const int col = n0 + wc * 64 + lcol;
      const float bv = (bias && ks == 0) ? bias[col] : 0.f;
#pragma unroll
      for (int j = 0; j < 4; j++) {
        const int lrow = m * 16 + lq * 4 + j;
        const int sc = lcol ^ (((lrow >> 2) & 3) << 4);   // write-conflict swizzle
        sC[lrow * 64 + sc] = f2bf(acc[m][n][j] + bv);
      }
    }
  // per-wave private region: compiler inserts lgkmcnt before dependent reads
  unsigned short* out = outP + (size_t)ks * M * N;
  const int rowbase = m0 + wr * WM, colbase = n0 + wc * 64;
  const int rr = lane >> 3, ch = lane & 7;
#pragma unroll
  for (int i = 0; i < WM / 8; i++) {
    const int row = i * 8 + rr;
    const int sb = (ch * 16) ^ (((row >> 2) & 3) << 5);   // byte-offset swizzle
    us8 v = *(const us8*)((const char*)sC + row * 128 + sb);
    *(us8*)(out + (size_t)(rowbase + row) * N + colbase + ch * 8) = v;
  }
}

// ---------------- chunked selective scan, LDS-staged from dt partials --------
// Block = 256 channels x TC=32 steps. Stage softplus(P0+P1) (sp) + x (bf16) +
// B/C (sum of partials, f32) to LDS; serial loop runs from LDS/registers only.
__global__ __launch_bounds__(256) void scan1_kernel(
    const unsigned short* __restrict__ DTP, const unsigned short* __restrict__ Hbf,
    const float* __restrict__ A_log, float* __restrict__ Hc, float* __restrict__ Pc) {
  const unsigned short* DT1 = DTP + (size_t)NROWS * NCOL;
  const int tid = threadIdx.x;
  const int d0 = blockIdx.x * 256, d = d0 + tid;
  const int b = blockIdx.y, c = blockIdx.z;
  __shared__ unsigned short ssp[TC][256];               // 16 KB
  __shared__ unsigned short sxx[TC][256];               // 16 KB
  __shared__ float sBC[TC][32];                         //  4 KB
  const size_t base = (size_t)b * LSEQ + c * TC;
#pragma unroll
  for (int it = 0; it < TC * 32 / 256; ++it) {          // 4 iters
    int idx = it * 256 + tid;
    int tt = idx >> 5, cc = (idx & 31) * 8;
    us8 a = *(const us8*)(DTP + (base + tt) * NCOL + d0 + cc);
    us8 bb = *(const us8*)(DT1 + (base + tt) * NCOL + d0 + cc);
    us8 o;
#pragma unroll
    for (int j = 0; j < 8; j++) o[j] = f2bf(softplusf_(bf2f(a[j]) + bf2f(bb[j])));
    *(us8*)&ssp[tt][cc] = o;
    *(us8*)&sxx[tt][cc] = *(const us8*)(Hbf + (base + tt) * DIN + d0 + cc);
  }
  if (tid < TC * 4) {                                   // BC: 4 us8 per row
    int tt = tid >> 2, cc = (tid & 3) * 8;
    us8 v0 = *(const us8*)(DTP + (base + tt) * NCOL + DIN + cc);
    us8 v1 = *(const us8*)(DT1 + (base + tt) * NCOL + DIN + cc);
#pragma unroll
    for (int j = 0; j < 8; j++) sBC[tt][cc + j] = bf2f(v0[j]) + bf2f(v1[j]);
  }
  float a2[16], h[16];
#pragma unroll
  for (int n = 0; n < 16; n++) {
    a2[n] = -__expf(A_log[(size_t)d * NSTATE + n]);     // natural scale
    h[n] = 0.f;
  }
  __syncthreads();
  float S = 0.f;
  for (int tt = 0; tt < TC; ++tt) {
    float sp = bf2f(ssp[tt][tid]);
    float x  = bf2f(sxx[tt][tid]);
    S += sp;
    float sx = sp * x;
#pragma unroll
    for (int n = 0; n < 16; n++)
      h[n] = fmaf(h[n], __expf(sp * a2[n]), sx * sBC[tt][n]);
  }
  const size_t chain = ((size_t)c * (NBATCH * DIN) + (size_t)b * DIN + d) * 16;
#pragma unroll
  for (int n = 0; n < 16; n++) {
    Hc[chain + n] = h[n];
    Pc[chain + n] = __expf(S * a2[n]);
  }
}

// combine: per (chain,n), sequential over chunks; in-place Hc -> chunk-init states.
__global__ __launch_bounds__(256) void scomb_kernel(float* __restrict__ Hc,
    const float* __restrict__ Pc) {
  const size_t id = (size_t)blockIdx.x * 256 + threadIdx.x;   // 65536 threads
  const size_t stride = (size_t)NBATCH * DIN * NSTATE;
  float h = 0.f;
  for (int c = 0; c < CCH; c++) {
    size_t o = (size_t)c * stride + id;
    float hl = Hc[o], p = Pc[o];
    Hc[o] = h;
    h = fmaf(p, h, hl);
  }
}

// scan2 + fused causal dwconv + SiLU + gate, LDS-staged:
// G = bf16((y_ssm + x*Dsk) * sigmoid(silu(conv(x)))), x = H (bf16).
__global__ __launch_bounds__(256) void scan2g_kernel(
    const unsigned short* __restrict__ DTP, const unsigned short* __restrict__ Hbf,
    const float* __restrict__ A_log, const float* __restrict__ Hinit,
    const float* __restrict__ cw, const float* __restrict__ cb,
    const float* __restrict__ dsk, unsigned short* __restrict__ G) {
  const unsigned short* DT1 = DTP + (size_t)NROWS * NCOL;
  const int tid = threadIdx.x;
  const int d0 = blockIdx.x * 256, d = d0 + tid;
  const int b = blockIdx.y, c = blockIdx.z;
  __shared__ unsigned short ssp[TC][256];
  __shared__ unsigned short sxx[TC][256];
  __shared__ float sBC[TC][32];
  const size_t base = (size_t)b * LSEQ + c * TC;
#pragma unroll
  for (int it = 0; it < TC * 32 / 256; ++it) {
    int idx = it * 256 + tid;
    int tt = idx >> 5, cc = (idx & 31) * 8;
    us8 a = *(const us8*)(DTP + (base + tt) * NCOL + d0 + cc);
    us8 bb = *(const us8*)(DT1 + (base + tt) * NCOL + d0 + cc);
    us8 o;
#pragma unroll
    for (int j = 0; j < 8; j++) o[j] = f2bf(softplusf_(bf2f(a[j]) + bf2f(bb[j])));
    *(us8*)&ssp[tt][cc] = o;
    *(us8*)&sxx[tt][cc] = *(const us8*)(Hbf + (base + tt) * DIN + d0 + cc);
  }
  if (tid < TC * 4) {
    int tt = tid >> 2, cc = (tid & 3) * 8;
    us8 v0 = *(const us8*)(DTP + (base + tt) * NCOL + DIN + cc);
    us8 v1 = *(const us8*)(DT1 + (base + tt) * NCOL + DIN + cc);
#pragma unroll
    for (int j = 0; j < 8; j++) sBC[tt][cc + j] = bf2f(v0[j]) + bf2f(v1[j]);
  }
  const size_t chain = ((size_t)c * (NBATCH * DIN) + (size_t)b * DIN + d) * 16;
  float a2[16], h[16];
#pragma unroll
  for (int n = 0; n < 16; n++) {
    a2[n] = -__expf(A_log[(size_t)d * NSTATE + n]);     // natural scale
    h[n] = Hinit[chain + n];
  }
  const float w0 = cw[d], w1 = cw[DIN + d], w2 = cw[2 * DIN + d], w3 = cw[3 * DIN + d];
  const float cbv = cb[d], dsv = dsk[d];
  const int t0 = c * TC;
  float xm1 = (t0 >= 1) ? bf2f(Hbf[(base - 1) * DIN + d]) : 0.f;
  float xm2 = (t0 >= 2) ? bf2f(Hbf[(base - 2) * DIN + d]) : 0.f;
  float xm3 = (t0 >= 3) ? bf2f(Hbf[(base - 3) * DIN + d]) : 0.f;
  __syncthreads();
  for (int tt = 0; tt < TC; ++tt) {
    float sp = bf2f(ssp[tt][tid]);
    float x  = bf2f(sxx[tt][tid]);
    float sx = sp * x;
    float y0 = 0.f, y1 = 0.f, y2 = 0.f, y3 = 0.f;
#pragma unroll
    for (int n = 0; n < 16; n += 4) {
      h[n]     = fmaf(h[n],     __expf(sp * a2[n]),     sx * sBC[tt][n]);
      h[n + 1] = fmaf(h[n + 1], __expf(sp * a2[n + 1]), sx * sBC[tt][n + 1]);
      h[n + 2] = fmaf(h[n + 2], __expf(sp * a2[n + 2]), sx * sBC[tt][n + 2]);
      h[n + 3] = fmaf(h[n + 3], __expf(sp * a2[n + 3]), sx * sBC[tt][n + 3]);
      y0 = fmaf(h[n],     sBC[tt][16 + n],     y0);
      y1 = fmaf(h[n + 1], sBC[tt][16 + n + 1], y1);
      y2 = fmaf(h[n + 2], sBC[tt][16 + n + 2], y2);
      y3 = fmaf(h[n + 3], sBC[tt][16 + n + 3], y3);
    }
    float y = (y0 + y1) + (y2 + y3);
    float a = cbv + w0 * xm3 + w1 * xm2 + w2 * xm1 + w3 * x;   // causal conv K=4
    float sl = a * sigmoidf_(a);                               // silu
    float g = (y + x * dsv) * sigmoidf_(sl);                   // gate
    G[(base + tt) * DIN + d] = f2bf(g);
    xm3 = xm2; xm2 = xm1; xm1 = x;
  }
}

// ---------------- launch ----------------
extern "C" void kernel_launch(void* const* d_in, const int* in_sizes, int n_in,
                              void* d_out, int out_size, void* d_ws, size_t ws_size,
                              hipStream_t stream) {
  const float* x_in   = (const float*)d_in[0];
  const float* pos    = (const float*)d_in[1];
  const float* norm_w = (const float*)d_in[2];
  const float* norm_b = (const float*)d_in[3];
  const float* Win    = (const float*)d_in[4];
  const float* b_in   = (const float*)d_in[5];
  const float* A_log  = (const float*)d_in[6];
  const float* Wdt    = (const float*)d_in[7];
  const float* b_dt   = (const float*)d_in[8];
  const float* WB     = (const float*)d_in[9];
  const float* WC     = (const float*)d_in[10];
  const float* Dsk    = (const float*)d_in[11];
  const float* conv_w = (const float*)d_in[12];
  const float* conv_b = (const float*)d_in[13];
  const float* Wout   = (const float*)d_in[14];
  const float* b_out  = (const float*)d_in[15];
  const float* fnw    = (const float*)d_in[16];
  const float* fnb    = (const float*)d_in[17];

  uint8_t* ws = (uint8_t*)d_ws;
  // Workspace (bytes). OFF_DT region: dt partials DTP (2 x 17.8MB, die after
  // scan2g) then WoutP (2 x 8.4MB) -- strictly sequential lifetimes.
  constexpr size_t OFF_X     = 0;                       // [4096][1024] f32   16.8 MB
  constexpr size_t OFF_HBF   = 16777216;                // [4096][2048] bf16  16.8 MB
  constexpr size_t OFF_DT    = 33554432;                // DTP / WoutP        35.7 MB
  constexpr size_t OFF_XG    = 69206016;                // Xn / Gb bf16       16.8 MB
  constexpr size_t OFF_HC    = 85983232;                // 16.8 MB (CCH=64)
  constexpr size_t OFF_PC    = 102760448;               // 16.8 MB
  constexpr size_t OFF_WINT  = 119537664;               // 2 x [2048][1024] bf16
  constexpr size_t OFF_WDT   = 127926272;               // 2 x [2176][2048] bf16
  constexpr size_t OFF_WOUT  = 145752064;               // 2 x [1024][2048] bf16
  constexpr size_t OFF_BIAS2 = 154140672;               // 2 x [2176] f32
  constexpr size_t WS_NEEDED = 154158080;
  if (ws_size < WS_NEEDED) return;

  float* X             = (float*)(ws + OFF_X);
  unsigned short* Hbf  = (unsigned short*)(ws + OFF_HBF);
  unsigned short* DTP  = (unsigned short*)(ws + OFF_DT);   // 2 x [4096][2176] bf16
  unsigned short* WoutP= (unsigned short*)(ws + OFF_DT);   // 2 x [4096][1024] bf16
  unsigned short* Xn   = (unsigned short*)(ws + OFF_XG);
  unsigned short* Gb   = (unsigned short*)(ws + OFF_XG);
  float* Hc            = (float*)(ws + OFF_HC);
  float* Pc            = (float*)(ws + OFF_PC);
  unsigned short* WinT   = (unsigned short*)(ws + OFF_WINT);
  unsigned short* WdtBCT = (unsigned short*)(ws + OFF_WDT);
  unsigned short* WoutT  = (unsigned short*)(ws + OFF_WOUT);
  float* bias2         = (float*)(ws + OFF_BIAS2);

  // ---- all weight prep up front, both layers (4 launches) ----
  tcvt_kernel<<<dim3(32, 16, 2), 256, 0, stream>>>(
      Win, WinT, 1024, 2048, (size_t)D_MODEL * DIN, (size_t)DIN * D_MODEL);
  tcvt_kernel<<<dim3(32, 32, 2), 256, 0, stream>>>(
      Wdt, WdtBCT, 2048, 2048, (size_t)DIN * DIN, (size_t)NCOL * DIN);
  tcvt_kernel<<<dim3(16, 32, 2), 256, 0, stream>>>(
      Wout, WoutT, 2048, 1024, (size_t)DIN * D_MODEL, (size_t)D_MODEL * DIN);
  wprep_kernel<<<dim3(361, 2), 256, 0, stream>>>(WB, WC, b_dt, WdtBCT, bias2);

  for (int i = 0; i < 2; i++) {
    unsigned short* WinT_i   = WinT + (size_t)i * DIN * D_MODEL;
    unsigned short* WdtBCT_i = WdtBCT + (size_t)i * NCOL * DIN;
    unsigned short* WoutT_i  = WoutT + (size_t)i * D_MODEL * DIN;
    float* bias2_i           = bias2 + (size_t)i * NCOL;

    // ---- LN (fuses pos-add at i=0; fuses prev Wout partials + residual at i=1)
    if (i == 0)
      ln_kernel<<<4096, 256, 0, stream>>>(x_in, pos, nullptr, 0, nullptr,
                                          norm_w, norm_b, Xn, nullptr, X);
    else
      ln_kernel<<<4096, 256, 0, stream>>>(X, nullptr, WoutP, 2, b_out,
                                          norm_w + D_MODEL, norm_b + D_MODEL,
                                          Xn, nullptr, X);
    // ---- Win: M=4096 N=2048 K=1024 unsplit, 128x128 tile -> 512 blocks
    gemm_kernel<64><<<dim3(16, 32, 1), 256, 0, stream>>>(
        Xn, WinT_i, b_in + (size_t)i * DIN, Hbf, NROWS, DIN, D_MODEL, 1024);
    // ---- dt: M=4096 N=2176 K=2048, 256x128 tile (wave 128x64), split-K=2
    //      -> 544 blocks, 42.7 FLOP/LDS-byte (LDS-BW fix)
    gemm_kernel<128><<<dim3(17, 16, 2), 256, 0, stream>>>(
        Hbf, WdtBCT_i, bias2_i, DTP, NROWS, NCOL, DIN, 1024);
    // ---- scan (LDS-staged; absorbs partial-sum + softplus)
    scan1_kernel<<<dim3(DIN / 256, NBATCH, CCH), 256, 0, stream>>>(
        DTP, Hbf, A_log + (size_t)i * DIN * NSTATE, Hc, Pc);
    scomb_kernel<<<(NBATCH * DIN * NSTATE) / 256, 256, 0, stream>>>(Hc, Pc);
    scan2g_kernel<<<dim3(DIN / 256, NBATCH, CCH), 256, 0, stream>>>(
        DTP, Hbf, A_log + (size_t)i * DIN * NSTATE, Hc,
        conv_w + (size_t)i * 4 * DIN, conv_b + (size_t)i * DIN,
        Dsk + (size_t)i * DIN, Gb);
    // ---- Wout: M=4096 N=1024 K=2048, split-K=2 -> 512 blocks
    gemm_kernel<64><<<dim3(8, 32, 2), 256, 0, stream>>>(
        Gb, WoutT_i, nullptr, WoutP, NROWS, D_MODEL, DIN, 1024);
  }

  // final LN fuses layer-2 Wout partials + b_out + residual
  ln_kernel<<<4096, 256, 0, stream>>>(X, nullptr, WoutP, 2, b_out + D_MODEL,
                                      fnw, fnb, nullptr, (float*)d_out, nullptr);
}

// Round 15
// 434.510 us; speedup vs baseline: 1.0408x; 1.0408x over previous
//
#include <hip/hip_runtime.h>
#include <hip/hip_cooperative_groups.h>
#include <cstdint>
#include <cstddef>

#define D_MODEL 1024
#define DIN     2048
#define NSTATE  16
#define LSEQ    2048
#define NBATCH  2
#define NROWS   (NBATCH*LSEQ)   // 4096
#define NCOL    (DIN + 128)     // 2176 = dt(2048) | B(16) | C(16) | pad(96)
#define CCH     64              // scan chunks
#define TC      (LSEQ/CCH)      // 32 steps per chunk

namespace cg = cooperative_groups;

typedef float  f32x4  __attribute__((ext_vector_type(4)));
typedef short  bf16x8 __attribute__((ext_vector_type(8)));
typedef unsigned short us8 __attribute__((ext_vector_type(8)));

__device__ __forceinline__ unsigned short f2bf(float f) {
  union { float f; unsigned u; } c; c.f = f;
  unsigned x = c.u + 0x7fffu + ((c.u >> 16) & 1u);   // RNE
  return (unsigned short)(x >> 16);
}
__device__ __forceinline__ float bf2f(unsigned short u) {
  union { unsigned u; float f; } c; c.u = (unsigned)u << 16; return c.f;
}
// native transcendentals (v_exp_f32 / v_log_f32 / v_rcp_f32), NOT precise libm
__device__ __forceinline__ float sigmoidf_(float x) {
  return __builtin_amdgcn_rcpf(1.f + __expf(-x));
}
__device__ __forceinline__ float softplusf_(float x) {   // fast, stable
  return fmaxf(x, 0.f) + __logf(1.f + __expf(-fabsf(x)));
}

// async global->LDS, 16B per lane; lds dest = wave-uniform base + lane*16
__device__ __forceinline__ void gll16(const void* g, void* l) {
  __builtin_amdgcn_global_load_lds(
      (const __attribute__((address_space(1))) void*)g,
      (__attribute__((address_space(3))) void*)l, 16, 0, 0);
}

// ---------------- layernorm (one row per block, D=1024) ----------------
// Optionally fuses: pos-add (pos!=null), Wout-partial sum + b_out (P!=null),
// residual update write (Xw!=null).
__global__ __launch_bounds__(256) void ln_kernel(const float* __restrict__ Xin,
    const float* __restrict__ pos, const unsigned short* __restrict__ P, int nP,
    const float* __restrict__ bex, const float* __restrict__ w,
    const float* __restrict__ b, unsigned short* __restrict__ outB,
    float* __restrict__ outF, float* __restrict__ Xw) {
  const int row = blockIdx.x, t = threadIdx.x;
  float4 v = *(const float4*)(Xin + (size_t)row * D_MODEL + t * 4);
  if (pos) {
    const float4 p = *(const float4*)(pos + (size_t)(row & (LSEQ - 1)) * D_MODEL + t * 4);
    v.x += p.x; v.y += p.y; v.z += p.z; v.w += p.w;
  }
  if (P) {
    const size_t MN = (size_t)NROWS * D_MODEL;
    const size_t e = (size_t)row * D_MODEL + t * 4;
    float a0 = 0.f, a1 = 0.f, a2 = 0.f, a3 = 0.f;
#pragma unroll 2
    for (int k = 0; k < nP; k++) {
      const ushort4 u = *(const ushort4*)(P + k * MN + e);
      a0 += bf2f(u.x); a1 += bf2f(u.y); a2 += bf2f(u.z); a3 += bf2f(u.w);
    }
    const float4 be = *(const float4*)(bex + t * 4);
    v.x += a0 + be.x; v.y += a1 + be.y; v.z += a2 + be.z; v.w += a3 + be.w;
  }
  if (Xw) *(float4*)(Xw + (size_t)row * D_MODEL + t * 4) = v;
  float s  = v.x + v.y + v.z + v.w;
  float s2 = v.x * v.x + v.y * v.y + v.z * v.z + v.w * v.w;
#pragma unroll
  for (int o = 1; o < 64; o <<= 1) { s += __shfl_xor(s, o, 64); s2 += __shfl_xor(s2, o, 64); }
  __shared__ float ps[8];
  int wv = t >> 6;
  if ((t & 63) == 0) { ps[wv] = s; ps[wv + 4] = s2; }
  __syncthreads();
  s  = ps[0] + ps[1] + ps[2] + ps[3];
  s2 = ps[4] + ps[5] + ps[6] + ps[7];
  float mean = s * (1.f / D_MODEL);
  float var  = s2 * (1.f / D_MODEL) - mean * mean;
  float rs   = rsqrtf(var + 1e-5f);
  const float4 wv4 = *(const float4*)(w + t * 4);
  const float4 bv4 = *(const float4*)(b + t * 4);
  float o0 = (v.x - mean) * rs * wv4.x + bv4.x;
  float o1 = (v.y - mean) * rs * wv4.y + bv4.y;
  float o2 = (v.z - mean) * rs * wv4.z + bv4.z;
  float o3 = (v.w - mean) * rs * wv4.w + bv4.w;
  if (outB) {
    ushort4 o; o.x = f2bf(o0); o.y = f2bf(o1); o.z = f2bf(o2); o.w = f2bf(o3);
    *(ushort4*)(outB + (size_t)row * D_MODEL + t * 4) = o;
  } else {
    float4 o; o.x = o0; o.y = o1; o.z = o2; o.w = o3;
    *(float4*)(outF + (size_t)row * D_MODEL + t * 4) = o;
  }
}

// ---------------- transpose + fp32->bf16: out[n][k] = in[k][n] ----------------
// blockIdx.z = layer (in/out advanced by per-layer strides).
__global__ __launch_bounds__(256) void tcvt_kernel(const float* __restrict__ in0,
    unsigned short* __restrict__ out0, int K_, int N_,
    size_t inLS, size_t outLS) {
  const float* in = in0 + (size_t)blockIdx.z * inLS;
  unsigned short* out = out0 + (size_t)blockIdx.z * outLS;
  __shared__ float tile[64][68];
  int n0 = blockIdx.x * 64, k0 = blockIdx.y * 64;
  int t = threadIdx.x;
  int r = t >> 4, cc = (t & 15) * 4;
#pragma unroll
  for (int j = 0; j < 4; j++) {
    const float4 v = *(const float4*)(in + (size_t)(k0 + r + j * 16) * N_ + n0 + cc);
    tile[r + j * 16][cc + 0] = v.x; tile[r + j * 16][cc + 1] = v.y;
    tile[r + j * 16][cc + 2] = v.z; tile[r + j * 16][cc + 3] = v.w;
  }
  __syncthreads();
  int nr = t >> 2, kc = (t & 3) * 16;
  unsigned u[8];
#pragma unroll
  for (int i = 0; i < 8; i++) {
    unsigned lo = f2bf(tile[kc + 2 * i][nr]);
    unsigned hi = f2bf(tile[kc + 2 * i + 1][nr]);
    u[i] = lo | (hi << 16);
  }
  uint4* dst = (uint4*)(out + (size_t)(n0 + nr) * K_ + k0 + kc);
  uint4 w0; w0.x = u[0]; w0.y = u[1]; w0.z = u[2]; w0.w = u[3];
  uint4 w1; w1.x = u[4]; w1.y = u[5]; w1.z = u[6]; w1.w = u[7];
  dst[0] = w0; dst[1] = w1;
}

// ---- merged prep: WB/WC^T rows 2048..2079, zero pad rows 2080..2175, bias2 ----
// blockIdx.y = layer.
__global__ __launch_bounds__(256) void wprep_kernel(const float* __restrict__ WB0,
    const float* __restrict__ WC0, const float* __restrict__ b_dt0,
    unsigned short* __restrict__ Wt0, float* __restrict__ bias20) {
  const int L = blockIdx.y;
  const float* WB = WB0 + (size_t)L * DIN * NSTATE;
  const float* WC = WC0 + (size_t)L * DIN * NSTATE;
  const float* b_dt = b_dt0 + (size_t)L * DIN;
  unsigned short* Wt = Wt0 + (size_t)L * NCOL * DIN;
  float* bias2 = bias20 + (size_t)L * NCOL;
  int id = blockIdx.x * 256 + threadIdx.x;
  if (id < 65536) {                                     // 32 x 2048 transpose fill
    int k = id & (DIN - 1);
    int n2 = id >> 11;
    float v = (n2 < NSTATE) ? WB[(size_t)k * NSTATE + n2]
                            : WC[(size_t)k * NSTATE + (n2 - NSTATE)];
    Wt[(size_t)(DIN + n2) * DIN + k] = f2bf(v);
  } else if (id < 90112) {                              // zero 96x2048 bf16, x8 vec
    int z = id - 65536;
    uint4 zz; zz.x = zz.y = zz.z = zz.w = 0u;
    *(uint4*)(Wt + (size_t)2080 * DIN + (size_t)z * 8) = zz;
  } else if (id < 90112 + NCOL) {                       // bias2
    int i = id - 90112;
    bias2[i] = (i < DIN) ? b_dt[i] : 0.f;
  }
}

// ---------------- bf16 MFMA GEMM, depth-2 pipeline (3 LDS bufs) -----------
// out[ks] = bf16(A[M][kRange] @ Bt[N][kRange]^T + bias(ks==0)).
// 128x128 tile, BK=32, 4 waves x (4x4) 16x16x32 frags. Counted vmcnt(4) keeps
// one STAGE in flight across two compute phases. K-col XOR swizzle on row bits
// 1-2 (bank-quad spread, conflict-free, r11). Epilogue bounces C through LDS
// for 16B coalesced stores. gridDim.z = split-K factor (1 = none).
// [r14 lesson: WM=128 wave-tile regressed -- 3 blk/CU residency beats ratio.]
__global__ __launch_bounds__(256) void gemm_kernel(
    const unsigned short* __restrict__ A, const unsigned short* __restrict__ Bt,
    const float* __restrict__ bias, unsigned short* __restrict__ outP,
    int M, int N, int Kfull, int kLen) {
  __shared__ unsigned short smem[6 * 128 * 32];        // sA:3x8KB | sB:3x8KB
  unsigned short* sA = smem;
  unsigned short* sB = smem + 3 * 4096;
  const int t = threadIdx.x;
  const int lane = t & 63, wave = t >> 6;
  const int wr = wave >> 1, wc = wave & 1;

  // XCD-chunked bijective swizzle over linearized 3D grid
  const int gx = gridDim.x, gy = gridDim.y;
  const int orig = (blockIdx.z * gy + blockIdx.y) * gx + blockIdx.x;
  const int nwg = gx * gy * gridDim.z;
  const int q = nwg >> 3, r = nwg & 7;
  const int xcd = orig & 7, pp = orig >> 3;
  const int wgid = (xcd < r) ? (xcd * (q + 1) + pp)
                             : (r * (q + 1) + (xcd - r) * q + pp);
  const int nt = wgid % gx;
  const int mt = (wgid / gx) % gy;
  const int ks = wgid / (gx * gy);
  const int m0 = mt * 128, n0 = nt * 128;

  const int ar = t >> 2;                               // staging row (0..63)
  const int acs = (((t & 3) ^ ((ar >> 1) & 3)) << 3);  // swizzled source K-col
  const int wseg = wave * 16 * 32;                     // wave-uniform LDS base
  const int lr = lane & 15;
  const int swA = (((lane >> 4) ^ ((lr >> 1) & 3)) << 3); // swizzled read K-col

  f32x4 acc[4][4];
#pragma unroll
  for (int m = 0; m < 4; m++)
#pragma unroll
    for (int n = 0; n < 4; n++) acc[m][n] = (f32x4)0.f;

  const int kBeg = ks * kLen;
  const int NT = kLen >> 5;

  auto STAGE = [&](int bi, int k0) {
    gll16(A  + (size_t)(m0 + ar) * Kfull + k0 + acs,      &sA[bi * 4096 + wseg]);
    gll16(A  + (size_t)(m0 + 64 + ar) * Kfull + k0 + acs, &sA[bi * 4096 + 64 * 32 + wseg]);
    gll16(Bt + (size_t)(n0 + ar) * Kfull + k0 + acs,      &sB[bi * 4096 + wseg]);
    gll16(Bt + (size_t)(n0 + 64 + ar) * Kfull + k0 + acs, &sB[bi * 4096 + 64 * 32 + wseg]);
  };
  auto COMPUTE = [&](int bi) {
    bf16x8 af[4], bg[4];
#pragma unroll
    for (int m = 0; m < 4; m++)
      af[m] = *(const bf16x8*)(&sA[bi * 4096 + (wr * 64 + m * 16 + lr) * 32 + swA]);
#pragma unroll
    for (int n = 0; n < 4; n++)
      bg[n] = *(const bf16x8*)(&sB[bi * 4096 + (wc * 64 + n * 16 + lr) * 32 + swA]);
#pragma unroll
    for (int m = 0; m < 4; m++)
#pragma unroll
      for (int n = 0; n < 4; n++)
        acc[m][n] = __builtin_amdgcn_mfma_f32_16x16x32_bf16(af[m], bg[n], acc[m][n], 0, 0, 0);
  };

  STAGE(0, kBeg); STAGE(1, kBeg + 32);                 // depth-2 prologue
  for (int tt = 0; tt < NT - 1; ++tt) {
    asm volatile("s_waitcnt vmcnt(4)" ::: "memory");   // oldest STAGE landed
    __builtin_amdgcn_s_barrier();                      // all waves' tile ready
    if (tt + 2 < NT) STAGE((tt + 2) % 3, kBeg + ((tt + 2) << 5));
    COMPUTE(tt % 3);
  }
  asm volatile("s_waitcnt vmcnt(0)" ::: "memory");     // tail drain
  __builtin_amdgcn_s_barrier();
  COMPUTE((NT - 1) % 3);

  // ---- epilogue: bounce C quadrant through LDS -> 16B coalesced stores ----
  __syncthreads();                                     // staging LDS now free
  unsigned short* sC = smem + wave * 4096;             // 64x64 bf16, 128B rows
  const int lq = lane >> 4;
#pragma unroll
  for (int m = 0; m < 4; m++)
#pragma unroll
    for (int n = 0; n < 4; n++) {
      const int lcol = n * 16 + lr;
      const int col = n0 + wc * 64 + lcol;
      const float bv = (bias && ks == 0) ? bias[col] : 0.f;
#pragma unroll
      for (int j = 0; j < 4; j++) {
        const int lrow = m * 16 + lq * 4 + j;
        const int sc = lcol ^ (((lrow >> 2) & 3) << 4);   // write-conflict swizzle
        sC[lrow * 64 + sc] = f2bf(acc[m][n][j] + bv);
      }
    }
  unsigned short* out = outP + (size_t)ks * M * N;
  const int rowbase = m0 + wr * 64, colbase = n0 + wc * 64;
  const int rr = lane >> 3, ch = lane & 7;
#pragma unroll
  for (int i = 0; i < 8; i++) {
    const int row = i * 8 + rr;
    const int sb = (ch * 16) ^ (((row >> 2) & 3) << 5);   // byte-offset swizzle
    us8 v = *(const us8*)((const char*)sC + row * 128 + sb);
    *(us8*)(out + (size_t)(rowbase + row) * N + colbase + ch * 8) = v;
  }
}

// ---------------- FUSED cooperative scan: scan1 + combine + scan2+gate --------
// Grid (DIN/256, NBATCH, CCH) = 1024 blocks, 36KB LDS -> 4 blocks/CU = exactly
// resident. Chunk data staged ONCE; two grid syncs replace two kernel launches
// and the scan2g global re-read. Numerically identical to the 3-kernel path.
__global__ __launch_bounds__(256) void scanfused_kernel(
    const unsigned short* __restrict__ DTP, const unsigned short* __restrict__ Hbf,
    const float* __restrict__ A_log, float* __restrict__ Hc, float* __restrict__ Pc,
    const float* __restrict__ cw, const float* __restrict__ cb,
    const float* __restrict__ dsk, unsigned short* __restrict__ G) {
  const unsigned short* DT1 = DTP + (size_t)NROWS * NCOL;
  const int tid = threadIdx.x;
  const int d0 = blockIdx.x * 256, d = d0 + tid;
  const int b = blockIdx.y, c = blockIdx.z;
  __shared__ unsigned short ssp[TC][256];               // 16 KB
  __shared__ unsigned short sxx[TC][256];               // 16 KB
  __shared__ float sBC[TC][32];                         //  4 KB
  const size_t base = (size_t)b * LSEQ + c * TC;
#pragma unroll
  for (int it = 0; it < TC * 32 / 256; ++it) {          // 4 iters
    int idx = it * 256 + tid;
    int tt = idx >> 5, cc = (idx & 31) * 8;
    us8 a = *(const us8*)(DTP + (base + tt) * NCOL + d0 + cc);
    us8 bb = *(const us8*)(DT1 + (base + tt) * NCOL + d0 + cc);
    us8 o;
#pragma unroll
    for (int j = 0; j < 8; j++) o[j] = f2bf(softplusf_(bf2f(a[j]) + bf2f(bb[j])));
    *(us8*)&ssp[tt][cc] = o;
    *(us8*)&sxx[tt][cc] = *(const us8*)(Hbf + (base + tt) * DIN + d0 + cc);
  }
  if (tid < TC * 4) {                                   // BC: 4 us8 per row
    int tt = tid >> 2, cc = (tid & 3) * 8;
    us8 v0 = *(const us8*)(DTP + (base + tt) * NCOL + DIN + cc);
    us8 v1 = *(const us8*)(DT1 + (base + tt) * NCOL + DIN + cc);
#pragma unroll
    for (int j = 0; j < 8; j++) sBC[tt][cc + j] = bf2f(v0[j]) + bf2f(v1[j]);
  }
  float a2[16], h[16];
#pragma unroll
  for (int n = 0; n < 16; n++) {
    a2[n] = -__expf(A_log[(size_t)d * NSTATE + n]);     // natural scale
    h[n] = 0.f;
  }
  // conv prologue state (independent global reads)
  const int t0 = c * TC;
  float xm1 = (t0 >= 1) ? bf2f(Hbf[(base - 1) * DIN + d]) : 0.f;
  float xm2 = (t0 >= 2) ? bf2f(Hbf[(base - 2) * DIN + d]) : 0.f;
  float xm3 = (t0 >= 3) ? bf2f(Hbf[(base - 3) * DIN + d]) : 0.f;
  const float w0 = cw[d], w1 = cw[DIN + d], w2 = cw[2 * DIN + d], w3 = cw[3 * DIN + d];
  const float cbv = cb[d], dsv = dsk[d];
  __syncthreads();

  // ---- phase 1: local scan from h=0 ----
  float S = 0.f;
  for (int tt = 0; tt < TC; ++tt) {
    float sp = bf2f(ssp[tt][tid]);
    float x  = bf2f(sxx[tt][tid]);
    S += sp;
    float sx = sp * x;
#pragma unroll
    for (int n = 0; n < 16; n++)
      h[n] = fmaf(h[n], __expf(sp * a2[n]), sx * sBC[tt][n]);
  }
  const size_t chain = ((size_t)c * (NBATCH * DIN) + (size_t)b * DIN + d) * 16;
#pragma unroll
  for (int n = 0; n < 16; n++) {
    Hc[chain + n] = h[n];
    Pc[chain + n] = __expf(S * a2[n]);
  }
  cg::this_grid().sync();

  // ---- phase 2: sequential chunk-combine (first 65536 threads) ----
  const int rank = (blockIdx.z * gridDim.y + blockIdx.y) * gridDim.x + blockIdx.x;
  if (rank < 256) {
    const size_t id = (size_t)rank * 256 + tid;
    const size_t stride = (size_t)NBATCH * DIN * NSTATE;
    float hh = 0.f;
    for (int cc2 = 0; cc2 < CCH; cc2++) {
      size_t o = (size_t)cc2 * stride + id;
      float hl = Hc[o], p = Pc[o];
      Hc[o] = hh;                                       // init state for chunk cc2
      hh = fmaf(p, hh, hl);
    }
  }
  cg::this_grid().sync();

  // ---- phase 3: replay from combined init + conv/SiLU/gate (LDS still live) --
#pragma unroll
  for (int n = 0; n < 16; n++) h[n] = Hc[chain + n];
  for (int tt = 0; tt < TC; ++tt) {
    float sp = bf2f(ssp[tt][tid]);
    float x  = bf2f(sxx[tt][tid]);
    float sx = sp * x;
    float y0 = 0.f, y1 = 0.f, y2 = 0.f, y3 = 0.f;
#pragma unroll
    for (int n = 0; n < 16; n += 4) {
      h[n]     = fmaf(h[n],     __expf(sp * a2[n]),     sx * sBC[tt][n]);
      h[n + 1] = fmaf(h[n + 1], __expf(sp * a2[n + 1]), sx * sBC[tt][n + 1]);
      h[n + 2] = fmaf(h[n + 2], __expf(sp * a2[n + 2]), sx * sBC[tt][n + 2]);
      h[n + 3] = fmaf(h[n + 3], __expf(sp * a2[n + 3]), sx * sBC[tt][n + 3]);
      y0 = fmaf(h[n],     sBC[tt][16 + n],     y0);
      y1 = fmaf(h[n + 1], sBC[tt][16 + n + 1], y1);
      y2 = fmaf(h[n + 2], sBC[tt][16 + n + 2], y2);
      y3 = fmaf(h[n + 3], sBC[tt][16 + n + 3], y3);
    }
    float y = (y0 + y1) + (y2 + y3);
    float a = cbv + w0 * xm3 + w1 * xm2 + w2 * xm1 + w3 * x;   // causal conv K=4
    float sl = a * sigmoidf_(a);                               // silu
    float g = (y + x * dsv) * sigmoidf_(sl);                   // gate
    G[(base + tt) * DIN + d] = f2bf(g);
    xm3 = xm2; xm2 = xm1; xm1 = x;
  }
}

// ---------------- fallback 3-kernel scan path (r13-proven) ----------------
__global__ __launch_bounds__(256) void scan1_kernel(
    const unsigned short* __restrict__ DTP, const unsigned short* __restrict__ Hbf,
    const float* __restrict__ A_log, float* __restrict__ Hc, float* __restrict__ Pc) {
  const unsigned short* DT1 = DTP + (size_t)NROWS * NCOL;
  const int tid = threadIdx.x;
  const int d0 = blockIdx.x * 256, d = d0 + tid;
  const int b = blockIdx.y, c = blockIdx.z;
  __shared__ unsigned short ssp[TC][256];
  __shared__ unsigned short sxx[TC][256];
  __shared__ float sBC[TC][32];
  const size_t base = (size_t)b * LSEQ + c * TC;
#pragma unroll
  for (int it = 0; it < TC * 32 / 256; ++it) {
    int idx = it * 256 + tid;
    int tt = idx >> 5, cc = (idx & 31) * 8;
    us8 a = *(const us8*)(DTP + (base + tt) * NCOL + d0 + cc);
    us8 bb = *(const us8*)(DT1 + (base + tt) * NCOL + d0 + cc);
    us8 o;
#pragma unroll
    for (int j = 0; j < 8; j++) o[j] = f2bf(softplusf_(bf2f(a[j]) + bf2f(bb[j])));
    *(us8*)&ssp[tt][cc] = o;
    *(us8*)&sxx[tt][cc] = *(const us8*)(Hbf + (base + tt) * DIN + d0 + cc);
  }
  if (tid < TC * 4) {
    int tt = tid >> 2, cc = (tid & 3) * 8;
    us8 v0 = *(const us8*)(DTP + (base + tt) * NCOL + DIN + cc);
    us8 v1 = *(const us8*)(DT1 + (base + tt) * NCOL + DIN + cc);
#pragma unroll
    for (int j = 0; j < 8; j++) sBC[tt][cc + j] = bf2f(v0[j]) + bf2f(v1[j]);
  }
  float a2[16], h[16];
#pragma unroll
  for (int n = 0; n < 16; n++) {
    a2[n] = -__expf(A_log[(size_t)d * NSTATE + n]);
    h[n] = 0.f;
  }
  __syncthreads();
  float S = 0.f;
  for (int tt = 0; tt < TC; ++tt) {
    float sp = bf2f(ssp[tt][tid]);
    float x  = bf2f(sxx[tt][tid]);
    S += sp;
    float sx = sp * x;
#pragma unroll
    for (int n = 0; n < 16; n++)
      h[n] = fmaf(h[n], __expf(sp * a2[n]), sx * sBC[tt][n]);
  }
  const size_t chain = ((size_t)c * (NBATCH * DIN) + (size_t)b * DIN + d) * 16;
#pragma unroll
  for (int n = 0; n < 16; n++) {
    Hc[chain + n] = h[n];
    Pc[chain + n] = __expf(S * a2[n]);
  }
}

__global__ __launch_bounds__(256) void scomb_kernel(float* __restrict__ Hc,
    const float* __restrict__ Pc) {
  const size_t id = (size_t)blockIdx.x * 256 + threadIdx.x;
  const size_t stride = (size_t)NBATCH * DIN * NSTATE;
  float h = 0.f;
  for (int c = 0; c < CCH; c++) {
    size_t o = (size_t)c * stride + id;
    float hl = Hc[o], p = Pc[o];
    Hc[o] = h;
    h = fmaf(p, h, hl);
  }
}

__global__ __launch_bounds__(256) void scan2g_kernel(
    const unsigned short* __restrict__ DTP, const unsigned short* __restrict__ Hbf,
    const float* __restrict__ A_log, const float* __restrict__ Hinit,
    const float* __restrict__ cw, const float* __restrict__ cb,
    const float* __restrict__ dsk, unsigned short* __restrict__ G) {
  const unsigned short* DT1 = DTP + (size_t)NROWS * NCOL;
  const int tid = threadIdx.x;
  const int d0 = blockIdx.x * 256, d = d0 + tid;
  const int b = blockIdx.y, c = blockIdx.z;
  __shared__ unsigned short ssp[TC][256];
  __shared__ unsigned short sxx[TC][256];
  __shared__ float sBC[TC][32];
  const size_t base = (size_t)b * LSEQ + c * TC;
#pragma unroll
  for (int it = 0; it < TC * 32 / 256; ++it) {
    int idx = it * 256 + tid;
    int tt = idx >> 5, cc = (idx & 31) * 8;
    us8 a = *(const us8*)(DTP + (base + tt) * NCOL + d0 + cc);
    us8 bb = *(const us8*)(DT1 + (base + tt) * NCOL + d0 + cc);
    us8 o;
#pragma unroll
    for (int j = 0; j < 8; j++) o[j] = f2bf(softplusf_(bf2f(a[j]) + bf2f(bb[j])));
    *(us8*)&ssp[tt][cc] = o;
    *(us8*)&sxx[tt][cc] = *(const us8*)(Hbf + (base + tt) * DIN + d0 + cc);
  }
  if (tid < TC * 4) {
    int tt = tid >> 2, cc = (tid & 3) * 8;
    us8 v0 = *(const us8*)(DTP + (base + tt) * NCOL + DIN + cc);
    us8 v1 = *(const us8*)(DT1 + (base + tt) * NCOL + DIN + cc);
#pragma unroll
    for (int j = 0; j < 8; j++) sBC[tt][cc + j] = bf2f(v0[j]) + bf2f(v1[j]);
  }
  const size_t chain = ((size_t)c * (NBATCH * DIN) + (size_t)b * DIN + d) * 16;
  float a2[16], h[16];
#pragma unroll
  for (int n = 0; n < 16; n++) {
    a2[n] = -__expf(A_log[(size_t)d * NSTATE + n]);
    h[n] = Hinit[chain + n];
  }
  const float w0 = cw[d], w1 = cw[DIN + d], w2 = cw[2 * DIN + d], w3 = cw[3 * DIN + d];
  const float cbv = cb[d], dsv = dsk[d];
  const int t0 = c * TC;
  float xm1 = (t0 >= 1) ? bf2f(Hbf[(base - 1) * DIN + d]) : 0.f;
  float xm2 = (t0 >= 2) ? bf2f(Hbf[(base - 2) * DIN + d]) : 0.f;
  float xm3 = (t0 >= 3) ? bf2f(Hbf[(base - 3) * DIN + d]) : 0.f;
  __syncthreads();
  for (int tt = 0; tt < TC; ++tt) {
    float sp = bf2f(ssp[tt][tid]);
    float x  = bf2f(sxx[tt][tid]);
    float sx = sp * x;
    float y0 = 0.f, y1 = 0.f, y2 = 0.f, y3 = 0.f;
#pragma unroll
    for (int n = 0; n < 16; n += 4) {
      h[n]     = fmaf(h[n],     __expf(sp * a2[n]),     sx * sBC[tt][n]);
      h[n + 1] = fmaf(h[n + 1], __expf(sp * a2[n + 1]), sx * sBC[tt][n + 1]);
      h[n + 2] = fmaf(h[n + 2], __expf(sp * a2[n + 2]), sx * sBC[tt][n + 2]);
      h[n + 3] = fmaf(h[n + 3], __expf(sp * a2[n + 3]), sx * sBC[tt][n + 3]);
      y0 = fmaf(h[n],     sBC[tt][16 + n],     y0);
      y1 = fmaf(h[n + 1], sBC[tt][16 + n + 1], y1);
      y2 = fmaf(h[n + 2], sBC[tt][16 + n + 2], y2);
      y3 = fmaf(h[n + 3], sBC[tt][16 + n + 3], y3);
    }
    float y = (y0 + y1) + (y2 + y3);
    float a = cbv + w0 * xm3 + w1 * xm2 + w2 * xm1 + w3 * x;
    float sl = a * sigmoidf_(a);
    float g = (y + x * dsv) * sigmoidf_(sl);
    G[(base + tt) * DIN + d] = f2bf(g);
    xm3 = xm2; xm2 = xm1; xm1 = x;
  }
}

// ---------------- launch ----------------
extern "C" void kernel_launch(void* const* d_in, const int* in_sizes, int n_in,
                              void* d_out, int out_size, void* d_ws, size_t ws_size,
                              hipStream_t stream) {
  const float* x_in   = (const float*)d_in[0];
  const float* pos    = (const float*)d_in[1];
  const float* norm_w = (const float*)d_in[2];
  const float* norm_b = (const float*)d_in[3];
  const float* Win    = (const float*)d_in[4];
  const float* b_in   = (const float*)d_in[5];
  const float* A_log  = (const float*)d_in[6];
  const float* Wdt    = (const float*)d_in[7];
  const float* b_dt   = (const float*)d_in[8];
  const float* WB     = (const float*)d_in[9];
  const float* WC     = (const float*)d_in[10];
  const float* Dsk    = (const float*)d_in[11];
  const float* conv_w = (const float*)d_in[12];
  const float* conv_b = (const float*)d_in[13];
  const float* Wout   = (const float*)d_in[14];
  const float* b_out  = (const float*)d_in[15];
  const float* fnw    = (const float*)d_in[16];
  const float* fnb    = (const float*)d_in[17];

  uint8_t* ws = (uint8_t*)d_ws;
  constexpr size_t OFF_X     = 0;                       // [4096][1024] f32   16.8 MB
  constexpr size_t OFF_HBF   = 16777216;                // [4096][2048] bf16  16.8 MB
  constexpr size_t OFF_DT    = 33554432;                // DTP / WoutP        35.7 MB
  constexpr size_t OFF_XG    = 69206016;                // Xn / Gb bf16       16.8 MB
  constexpr size_t OFF_HC    = 85983232;                // 16.8 MB (CCH=64)
  constexpr size_t OFF_PC    = 102760448;               // 16.8 MB
  constexpr size_t OFF_WINT  = 119537664;               // 2 x [2048][1024] bf16
  constexpr size_t OFF_WDT   = 127926272;               // 2 x [2176][2048] bf16
  constexpr size_t OFF_WOUT  = 145752064;               // 2 x [1024][2048] bf16
  constexpr size_t OFF_BIAS2 = 154140672;               // 2 x [2176] f32
  constexpr size_t WS_NEEDED = 154158080;
  if (ws_size < WS_NEEDED) return;

  float* X             = (float*)(ws + OFF_X);
  unsigned short* Hbf  = (unsigned short*)(ws + OFF_HBF);
  unsigned short* DTP  = (unsigned short*)(ws + OFF_DT);   // 2 x [4096][2176] bf16
  unsigned short* WoutP= (unsigned short*)(ws + OFF_DT);   // 2 x [4096][1024] bf16
  unsigned short* Xn   = (unsigned short*)(ws + OFF_XG);
  unsigned short* Gb   = (unsigned short*)(ws + OFF_XG);
  float* Hc            = (float*)(ws + OFF_HC);
  float* Pc            = (float*)(ws + OFF_PC);
  unsigned short* WinT   = (unsigned short*)(ws + OFF_WINT);
  unsigned short* WdtBCT = (unsigned short*)(ws + OFF_WDT);
  unsigned short* WoutT  = (unsigned short*)(ws + OFF_WOUT);
  float* bias2         = (float*)(ws + OFF_BIAS2);

  // cooperative fused scan requires all 1024 blocks resident (4/CU @ 36KB LDS)
  int maxB = 0, coopOK = 0;
  if (hipOccupancyMaxActiveBlocksPerMultiprocessor(
          &maxB, (const void*)scanfused_kernel, 256, 0) == hipSuccess && maxB >= 4)
    coopOK = 1;

  // ---- all weight prep up front, both layers (4 launches) ----
  tcvt_kernel<<<dim3(32, 16, 2), 256, 0, stream>>>(
      Win, WinT, 1024, 2048, (size_t)D_MODEL * DIN, (size_t)DIN * D_MODEL);
  tcvt_kernel<<<dim3(32, 32, 2), 256, 0, stream>>>(
      Wdt, WdtBCT, 2048, 2048, (size_t)DIN * DIN, (size_t)NCOL * DIN);
  tcvt_kernel<<<dim3(16, 32, 2), 256, 0, stream>>>(
      Wout, WoutT, 2048, 1024, (size_t)DIN * D_MODEL, (size_t)D_MODEL * DIN);
  wprep_kernel<<<dim3(361, 2), 256, 0, stream>>>(WB, WC, b_dt, WdtBCT, bias2);

  for (int i = 0; i < 2; i++) {
    unsigned short* WinT_i   = WinT + (size_t)i * DIN * D_MODEL;
    unsigned short* WdtBCT_i = WdtBCT + (size_t)i * NCOL * DIN;
    unsigned short* WoutT_i  = WoutT + (size_t)i * D_MODEL * DIN;
    float* bias2_i           = bias2 + (size_t)i * NCOL;
    const float* alog_i = A_log + (size_t)i * DIN * NSTATE;
    const float* cw_i   = conv_w + (size_t)i * 4 * DIN;
    const float* cb_i   = conv_b + (size_t)i * DIN;
    const float* ds_i   = Dsk + (size_t)i * DIN;

    // ---- LN (fuses pos-add at i=0; fuses prev Wout partials + residual at i=1)
    if (i == 0)
      ln_kernel<<<4096, 256, 0, stream>>>(x_in, pos, nullptr, 0, nullptr,
                                          norm_w, norm_b, Xn, nullptr, X);
    else
      ln_kernel<<<4096, 256, 0, stream>>>(X, nullptr, WoutP, 2, b_out,
                                          norm_w + D_MODEL, norm_b + D_MODEL,
                                          Xn, nullptr, X);
    // ---- Win: M=4096 N=2048 K=1024 unsplit -> 512 blocks, bias fused
    gemm_kernel<<<dim3(16, 32, 1), 256, 0, stream>>>(
        Xn, WinT_i, b_in + (size_t)i * DIN, Hbf, NROWS, DIN, D_MODEL, 1024);
    // ---- dt: M=4096 N=2176 K=2048, split-K=2 -> 1088 blocks (3/CU resident)
    gemm_kernel<<<dim3(17, 32, 2), 256, 0, stream>>>(
        Hbf, WdtBCT_i, bias2_i, DTP, NROWS, NCOL, DIN, 1024);
    // ---- scan (fused cooperative when resident; else 3-kernel fallback)
    if (coopOK) {
      const unsigned short* DTPc = DTP;
      const unsigned short* Hbfc = Hbf;
      unsigned short* Gc = Gb;
      void* args[] = {(void*)&DTPc, (void*)&Hbfc, (void*)&alog_i, (void*)&Hc,
                      (void*)&Pc, (void*)&cw_i, (void*)&cb_i, (void*)&ds_i,
                      (void*)&Gc};
      hipLaunchCooperativeKernel((const void*)scanfused_kernel,
                                 dim3(DIN / 256, NBATCH, CCH), dim3(256),
                                 args, 0, stream);
    } else {
      scan1_kernel<<<dim3(DIN / 256, NBATCH, CCH), 256, 0, stream>>>(
          DTP, Hbf, alog_i, Hc, Pc);
      scomb_kernel<<<(NBATCH * DIN * NSTATE) / 256, 256, 0, stream>>>(Hc, Pc);
      scan2g_kernel<<<dim3(DIN / 256, NBATCH, CCH), 256, 0, stream>>>(
          DTP, Hbf, alog_i, Hc, cw_i, cb_i, ds_i, Gb);
    }
    // ---- Wout: M=4096 N=1024 K=2048, split-K=2 -> 512 blocks
    gemm_kernel<<<dim3(8, 32, 2), 256, 0, stream>>>(
        Gb, WoutT_i, nullptr, WoutP, NROWS, D_MODEL, DIN, 1024);
  }

  // final LN fuses layer-2 Wout partials + b_out + residual
  ln_kernel<<<4096, 256, 0, stream>>>(X, nullptr, WoutP, 2, b_out + D_MODEL,
                                      fnw, fnb, nullptr, (float*)d_out, nullptr);
}